// Round 1
// baseline (215.308 us; speedup 1.0000x reference)
//
#include <hip/hip_runtime.h>
#include <math.h>

// Problem: B=2048, K=256, D=512, all fp32.
// out[b,d] = 1 / (sum_k exp(-0.5 * sum_d' (x[b,d']-c[k,d'])^2 * bw[k,d']) * softplus(W)[k,d] + 1e-3)

#define B_SZ 2048
#define K_SZ 256
#define D_SZ 512
#define EPS  1e-3f
#define TB   8   // rows of x per block

// Precompute softplus(raw_weights) once into workspace (K*D fp32 = 512 KB).
__global__ __launch_bounds__(256) void softplus_kernel(const float* __restrict__ raw,
                                                       float* __restrict__ wsp) {
    int i = blockIdx.x * 256 + threadIdx.x;
    if (i < K_SZ * D_SZ) {
        float v = raw[i];
        // stable softplus: max(x,0) + log1p(exp(-|x|))
        wsp[i] = fmaxf(v, 0.f) + log1pf(__expf(-fabsf(v)));
    }
}

// Fused: distances -> exp -> matmul -> reciprocal. One block = TB rows of x.
// 512 threads (8 waves). grid = B/TB = 256 blocks (1 block/CU).
__global__ __launch_bounds__(512) void fused_kernel(
    const float* __restrict__ x, const float* __restrict__ centers,
    const float* __restrict__ bandwidths, const float* __restrict__ raw_w,
    const float* __restrict__ wsp, float* __restrict__ out, int pre)
{
    // xs padded +4 floats: row stride 516 dwords -> rows start on distinct banks
    // (516 % 32 == 4), 16B-aligned (516 % 4 == 0) so b128 reads stay legal.
    __shared__ float xs[TB][D_SZ + 4];
    // rbfT[k][r]: phase-2 writes are lane-contiguous (addr = kc*512 + t),
    // phase-3 reads are same-address broadcast across the wave.
    __shared__ float rbfT[K_SZ][TB];

    const int t  = threadIdx.x;
    const int b0 = blockIdx.x * TB;

    // ---- Phase 1: stage x tile (TB x 512 fp32) into LDS, coalesced float4 ----
    {
        const float4* xg = (const float4*)(x + (size_t)b0 * D_SZ);
        #pragma unroll
        for (int i = 0; i < 2; ++i) {
            int idx  = t + i * 512;          // float4 index in tile (0..1023)
            int row  = idx >> 7;             // 128 float4 per row
            int col4 = idx & 127;
            float4 v = xg[idx];
            *(float4*)&xs[row][col4 << 2] = v;
        }
    }
    __syncthreads();

    // ---- Phase 2: dist[r][k] and rbf = exp(-0.5*dist) ----
    // thread -> (r = t&7, kslot = t>>3); 4 k-chunks cover all 256 k.
    // Wave reads xs at 8 distinct row addresses -> 8 distinct bank groups, no conflict.
    {
        const int r     = t & 7;
        const int kslot = t >> 3;
        #pragma unroll
        for (int kc = 0; kc < 4; ++kc) {
            int k = kc * 64 + kslot;
            const float4* cg = (const float4*)(centers    + (size_t)k * D_SZ);
            const float4* bg = (const float4*)(bandwidths + (size_t)k * D_SZ);
            float acc = 0.f;
            #pragma unroll 8
            for (int j = 0; j < 128; ++j) {
                float4 c  = cg[j];
                float4 w  = bg[j];
                float4 xv = *(const float4*)&xs[r][j << 2];
                float d0 = xv.x - c.x, d1 = xv.y - c.y;
                float d2 = xv.z - c.z, d3 = xv.w - c.w;
                acc = fmaf(d0 * d0, w.x, acc);
                acc = fmaf(d1 * d1, w.y, acc);
                acc = fmaf(d2 * d2, w.z, acc);
                acc = fmaf(d3 * d3, w.w, acc);
            }
            rbfT[k][r] = __expf(-0.5f * acc);
        }
    }
    __syncthreads();

    // ---- Phase 3: h[r][d=t] = sum_k rbf[r][k] * softplus(W)[k][t]; out = 1/(h+eps) ----
    {
        float acc[TB];
        #pragma unroll
        for (int i = 0; i < TB; ++i) acc[i] = 0.f;

        for (int k = 0; k < K_SZ; ++k) {
            float w;
            if (pre) {
                w = wsp[(size_t)k * D_SZ + t];          // coalesced
            } else {
                float rw = raw_w[(size_t)k * D_SZ + t];
                w = fmaxf(rw, 0.f) + log1pf(__expf(-fabsf(rw)));
            }
            float4 r0 = *(const float4*)&rbfT[k][0];    // broadcast
            float4 r1 = *(const float4*)&rbfT[k][4];
            acc[0] = fmaf(r0.x, w, acc[0]);
            acc[1] = fmaf(r0.y, w, acc[1]);
            acc[2] = fmaf(r0.z, w, acc[2]);
            acc[3] = fmaf(r0.w, w, acc[3]);
            acc[4] = fmaf(r1.x, w, acc[4]);
            acc[5] = fmaf(r1.y, w, acc[5]);
            acc[6] = fmaf(r1.z, w, acc[6]);
            acc[7] = fmaf(r1.w, w, acc[7]);
        }
        #pragma unroll
        for (int r2 = 0; r2 < TB; ++r2) {
            out[(size_t)(b0 + r2) * D_SZ + t] = 1.f / (acc[r2] + EPS);
        }
    }
}

extern "C" void kernel_launch(void* const* d_in, const int* in_sizes, int n_in,
                              void* d_out, int out_size, void* d_ws, size_t ws_size,
                              hipStream_t stream) {
    const float* x          = (const float*)d_in[0];
    const float* centers    = (const float*)d_in[1];
    const float* bandwidths = (const float*)d_in[2];
    const float* raw_w      = (const float*)d_in[3];
    float* out = (float*)d_out;
    float* wsp = (float*)d_ws;

    // Use workspace for precomputed softplus weights if it fits (512 KB).
    const int pre = (ws_size >= (size_t)K_SZ * D_SZ * sizeof(float)) ? 1 : 0;
    if (pre) {
        softplus_kernel<<<(K_SZ * D_SZ + 255) / 256, 256, 0, stream>>>(raw_w, wsp);
    }
    fused_kernel<<<B_SZ / TB, 512, 0, stream>>>(x, centers, bandwidths, raw_w, wsp, out, pre);
}

// Round 2
// 135.213 us; speedup vs baseline: 1.5924x; 1.5924x over previous
//
#include <hip/hip_runtime.h>
#include <math.h>

// Problem: B=2048, K=256, D=512, all fp32.
// out[b,d] = 1 / (sum_k exp(-0.5 * sum_d' (x[b,d']-c[k,d'])^2 * bw[k,d']) * softplus(W)[k,d] + 1e-3)

#define B_SZ 2048
#define K_SZ 256
#define D_SZ 512
#define EPS  1e-3f
#define TB   8   // rows of x per block

// Precompute softplus(raw_weights) once into workspace (K*D fp32 = 512 KB).
__global__ __launch_bounds__(256) void softplus_kernel(const float* __restrict__ raw,
                                                       float* __restrict__ wsp) {
    int i = blockIdx.x * 256 + threadIdx.x;
    if (i < K_SZ * D_SZ) {
        float v = raw[i];
        wsp[i] = fmaxf(v, 0.f) + log1pf(__expf(-fabsf(v)));
    }
}

// Fused: distances -> exp -> matmul -> reciprocal.
// 1024 threads (16 waves), TB=8 rows per block, grid = 256 blocks (1 block/CU,
// 16 waves/CU). __launch_bounds__(1024,4): VGPR cap 128 so phase-2 unroll can
// keep ~16 float4 loads in flight (round-1's 36-VGPR build could hold ~4).
__global__ __launch_bounds__(1024, 4) void fused_kernel(
    const float* __restrict__ x, const float* __restrict__ centers,
    const float* __restrict__ bandwidths, const float* __restrict__ raw_w,
    const float* __restrict__ wsp, float* __restrict__ out, int pre)
{
    // xs padded +4 floats: row stride 516 dwords -> rows on distinct banks,
    // 16B-aligned so b128 reads stay legal.
    __shared__ float xs[TB][D_SZ + 4];
    // rbfT[k][r]: phase-2 writes lane-contiguous, phase-3 reads broadcast.
    __shared__ float rbfT[K_SZ][TB];

    const int t  = threadIdx.x;
    const int b0 = blockIdx.x * TB;

    // ---- Phase 1: stage x tile (8 x 512 fp32), one float4 per thread ----
    {
        const float4* xg = (const float4*)(x + (size_t)b0 * D_SZ);
        int row  = t >> 7;           // 128 float4 per row
        int col4 = t & 127;
        float4 v = xg[t];
        *(float4*)&xs[row][col4 << 2] = v;
    }
    __syncthreads();

    // ---- Phase 2: dist[r][k], rbf = exp(-0.5*dist) ----
    // r = t&7, kslot = t>>3 (128 slots); 2 chunks cover K=256.
    // Lanes 0..7 share kslot -> c/bw loads are 8-distinct-row broadcasts.
    // 4 independent accumulators break the FMA dependency chain.
    {
        const int r     = t & 7;
        const int kslot = t >> 3;
        #pragma unroll
        for (int kc = 0; kc < 2; ++kc) {
            int k = kc * 128 + kslot;
            const float4* cg = (const float4*)(centers    + (size_t)k * D_SZ);
            const float4* bg = (const float4*)(bandwidths + (size_t)k * D_SZ);
            float a0 = 0.f, a1 = 0.f, a2 = 0.f, a3 = 0.f;
            #pragma unroll 8
            for (int j = 0; j < 128; ++j) {
                float4 c  = cg[j];
                float4 w  = bg[j];
                float4 xv = *(const float4*)&xs[r][j << 2];
                float d0 = xv.x - c.x, d1 = xv.y - c.y;
                float d2 = xv.z - c.z, d3 = xv.w - c.w;
                a0 = fmaf(d0 * d0, w.x, a0);
                a1 = fmaf(d1 * d1, w.y, a1);
                a2 = fmaf(d2 * d2, w.z, a2);
                a3 = fmaf(d3 * d3, w.w, a3);
            }
            rbfT[k][r] = __expf(-0.5f * ((a0 + a1) + (a2 + a3)));
        }
    }
    __syncthreads();

    // ---- Phase 3: h[r][d] = sum_k rbf[r][k]*softplus(W)[k][d]; out=1/(h+eps) ----
    // Two 512-thread halves each cover 4 rows for all 512 d's.
    // rbfT read is a single-address float4 broadcast per wave.
    {
        const int d    = t & 511;
        const int half = t >> 9;
        float acc0 = 0.f, acc1 = 0.f, acc2 = 0.f, acc3 = 0.f;

        if (pre) {
            #pragma unroll 8
            for (int k = 0; k < K_SZ; ++k) {
                float w = wsp[(size_t)k * D_SZ + d];            // coalesced, L2-hit
                float4 rv = *(const float4*)&rbfT[k][half << 2]; // broadcast
                acc0 = fmaf(rv.x, w, acc0);
                acc1 = fmaf(rv.y, w, acc1);
                acc2 = fmaf(rv.z, w, acc2);
                acc3 = fmaf(rv.w, w, acc3);
            }
        } else {
            #pragma unroll 4
            for (int k = 0; k < K_SZ; ++k) {
                float rw = raw_w[(size_t)k * D_SZ + d];
                float w = fmaxf(rw, 0.f) + log1pf(__expf(-fabsf(rw)));
                float4 rv = *(const float4*)&rbfT[k][half << 2];
                acc0 = fmaf(rv.x, w, acc0);
                acc1 = fmaf(rv.y, w, acc1);
                acc2 = fmaf(rv.z, w, acc2);
                acc3 = fmaf(rv.w, w, acc3);
            }
        }

        const int rbase = b0 + (half << 2);
        out[(size_t)(rbase + 0) * D_SZ + d] = 1.f / (acc0 + EPS);
        out[(size_t)(rbase + 1) * D_SZ + d] = 1.f / (acc1 + EPS);
        out[(size_t)(rbase + 2) * D_SZ + d] = 1.f / (acc2 + EPS);
        out[(size_t)(rbase + 3) * D_SZ + d] = 1.f / (acc3 + EPS);
    }
}

extern "C" void kernel_launch(void* const* d_in, const int* in_sizes, int n_in,
                              void* d_out, int out_size, void* d_ws, size_t ws_size,
                              hipStream_t stream) {
    const float* x          = (const float*)d_in[0];
    const float* centers    = (const float*)d_in[1];
    const float* bandwidths = (const float*)d_in[2];
    const float* raw_w      = (const float*)d_in[3];
    float* out = (float*)d_out;
    float* wsp = (float*)d_ws;

    const int pre = (ws_size >= (size_t)K_SZ * D_SZ * sizeof(float)) ? 1 : 0;
    if (pre) {
        softplus_kernel<<<(K_SZ * D_SZ + 255) / 256, 256, 0, stream>>>(raw_w, wsp);
    }
    fused_kernel<<<B_SZ / TB, 1024, 0, stream>>>(x, centers, bandwidths, raw_w, wsp, out, pre);
}

// Round 3
// 85.519 us; speedup vs baseline: 2.5177x; 1.5811x over previous
//
#include <hip/hip_runtime.h>
#include <math.h>

// Problem: B=2048, K=256, D=512, all fp32.
// out[b,d] = 1 / (sum_k exp(-0.5 * sum_d' (x[b,d']-c[k,d'])^2 * bw[k,d']) * softplus(W)[k,d] + 1e-3)
//
// MFMA formulation:
//   dist[b,k] = (A1 @ B1t^T)[b,k] + P[k]
//     A1  (2048 x 1024) bf16: cols [0,512)=x^2, [512,1024)=x
//     B1t ( 256 x 1024) bf16: cols [0,512)=bw,  [512,1024)=-2*c*bw   (row-major N x K)
//     P   (256) fp32: sum_d c^2*bw
//   R[b,k] = bf16(exp(-0.5*dist))
//   h = R (2048x256) @ WspT^T   with WspT (512 x 256) bf16 = softplus(W) transposed
//   out = 1/(h+eps)

#define B_SZ 2048
#define K_SZ 256
#define D_SZ 512
#define EPS  1e-3f

typedef __attribute__((ext_vector_type(8))) short bf16x8;   // 8 bf16 = 4 VGPRs
typedef __attribute__((ext_vector_type(4))) float f32x4;

// Workspace layout (bytes)
#define A1_OFF    0u          // bf16 [2048][1024]  = 4,194,304 B
#define B1T_OFF   4194304u    // bf16 [ 256][1024]  =   524,288 B
#define WSPT_OFF  4718592u    // bf16 [ 512][ 256]  =   262,144 B
#define P_OFF     4980736u    // fp32 [256]         =     1,024 B
#define R_OFF     4981760u    // bf16 [2048][ 256]  = 1,048,576 B
#define WS_TOTAL  6030336u

__device__ inline unsigned short f2bf(float f) {
    unsigned int u = __builtin_bit_cast(unsigned int, f);
    u += 0x7FFFu + ((u >> 16) & 1u);          // round-to-nearest-even
    return (unsigned short)(u >> 16);
}

__device__ inline float softplus_f(float v) {
    return fmaxf(v, 0.f) + log1pf(__expf(-fabsf(v)));
}

// ---------------- Prep: build A1, B1t, WspT, P in one kernel ----------------
// grid = 1344 blocks x 256 threads, partitioned by blockIdx.x:
//   [0,1024)    A1   : 2048*512 elems, float4 per thread
//   [1024,1152) B1t  : 256*512 elems,  float4 per thread
//   [1152,1280) WspT : 512*256 elems,  4 scalar elems per thread (transpose)
//   [1280,1344) P    : 4 k per block, one wave each
__global__ __launch_bounds__(256) void prep_kernel(
    const float* __restrict__ x, const float* __restrict__ centers,
    const float* __restrict__ bandwidths, const float* __restrict__ raw_w,
    unsigned char* __restrict__ ws)
{
    const int bid = blockIdx.x;
    const int t   = threadIdx.x;

    if (bid < 1024) {                       // ---- A1 ----
        unsigned short* a1 = (unsigned short*)(ws + A1_OFF);
        int idx4 = bid * 256 + t;           // float4 index
        int e = idx4 * 4;
        int b = e >> 9, d = e & 511;
        float4 xv = *(const float4*)(x + e);
        ushort4 sq, li;
        sq.x = f2bf(xv.x * xv.x); sq.y = f2bf(xv.y * xv.y);
        sq.z = f2bf(xv.z * xv.z); sq.w = f2bf(xv.w * xv.w);
        li.x = f2bf(xv.x); li.y = f2bf(xv.y); li.z = f2bf(xv.z); li.w = f2bf(xv.w);
        *(ushort4*)(a1 + (size_t)b * 1024 + d)       = sq;
        *(ushort4*)(a1 + (size_t)b * 1024 + 512 + d) = li;
    } else if (bid < 1152) {                // ---- B1t ----
        unsigned short* b1 = (unsigned short*)(ws + B1T_OFF);
        int idx4 = (bid - 1024) * 256 + t;
        int e = idx4 * 4;
        int k = e >> 9, d = e & 511;
        float4 cv = *(const float4*)(centers + e);
        float4 wv = *(const float4*)(bandwidths + e);
        ushort4 bw, cc;
        bw.x = f2bf(wv.x); bw.y = f2bf(wv.y); bw.z = f2bf(wv.z); bw.w = f2bf(wv.w);
        cc.x = f2bf(-2.f * cv.x * wv.x); cc.y = f2bf(-2.f * cv.y * wv.y);
        cc.z = f2bf(-2.f * cv.z * wv.z); cc.w = f2bf(-2.f * cv.w * wv.w);
        *(ushort4*)(b1 + (size_t)k * 1024 + d)       = bw;
        *(ushort4*)(b1 + (size_t)k * 1024 + 512 + d) = cc;
    } else if (bid < 1280) {                // ---- WspT (transpose) ----
        unsigned short* wt = (unsigned short*)(ws + WSPT_OFF);
        int base = (bid - 1152) * 1024;
        #pragma unroll
        for (int i = 0; i < 4; ++i) {
            int idx = base + i * 256 + t;   // linear index into WspT (d-major)
            int d = idx >> 8, k = idx & 255;
            float rw = raw_w[(size_t)k * D_SZ + d];   // strided read, L2 absorbs
            wt[idx] = f2bf(softplus_f(rw));           // coalesced 2B write
        }
    } else {                                // ---- P[k] = sum_d c^2*bw ----
        float* P = (float*)(ws + P_OFF);
        int w = t >> 6, lane = t & 63;
        int k = (bid - 1280) * 4 + w;
        const float* cg = centers    + (size_t)k * D_SZ;
        const float* bg = bandwidths + (size_t)k * D_SZ;
        float s = 0.f;
        #pragma unroll
        for (int j = 0; j < 8; ++j) {
            int d = lane + 64 * j;
            float c = cg[d];
            s = fmaf(c * c, bg[d], s);
        }
        #pragma unroll
        for (int off = 32; off > 0; off >>= 1) s += __shfl_down(s, off);
        if (lane == 0) P[k] = s;
    }
}

// ---------------- GEMM1: dist = A1 @ B1t^T + P ; R = bf16(exp(-.5*dist)) ----
// Wave tile 16x32 (1 A frag, 2 B frags). Block = 4 waves stacked in M (64x32).
// grid = (2048/64, 256/32) = (32, 8) = 256 blocks.
__global__ __launch_bounds__(256) void gemm1_kernel(const unsigned char* __restrict__ ws_ro,
                                                    unsigned char* __restrict__ ws)
{
    const unsigned short* A1  = (const unsigned short*)(ws_ro + A1_OFF);
    const unsigned short* B1t = (const unsigned short*)(ws_ro + B1T_OFF);
    const float*          P   = (const float*)(ws_ro + P_OFF);
    unsigned short*       R   = (unsigned short*)(ws + R_OFF);

    const int lane = threadIdx.x & 63;
    const int w    = threadIdx.x >> 6;
    const int l16  = lane & 15;
    const int quad = lane >> 4;
    const int m0 = blockIdx.x * 64 + w * 16;
    const int n0 = blockIdx.y * 32;

    const unsigned short* aptr  = A1  + (size_t)(m0 + l16) * 1024 + quad * 8;
    const unsigned short* bptr0 = B1t + (size_t)(n0 + l16) * 1024 + quad * 8;
    const unsigned short* bptr1 = bptr0 + 16 * 1024;

    f32x4 acc0 = {0.f, 0.f, 0.f, 0.f}, acc1 = {0.f, 0.f, 0.f, 0.f};
    #pragma unroll 4
    for (int ks = 0; ks < 1024; ks += 32) {
        bf16x8 af  = *(const bf16x8*)(aptr + ks);
        bf16x8 bf0 = *(const bf16x8*)(bptr0 + ks);
        bf16x8 bf1 = *(const bf16x8*)(bptr1 + ks);
        acc0 = __builtin_amdgcn_mfma_f32_16x16x32_bf16(af, bf0, acc0, 0, 0, 0);
        acc1 = __builtin_amdgcn_mfma_f32_16x16x32_bf16(af, bf1, acc1, 0, 0, 0);
    }

    const float p0 = P[n0 + l16];
    const float p1 = P[n0 + 16 + l16];
    #pragma unroll
    for (int r = 0; r < 4; ++r) {
        int row = quad * 4 + r;
        unsigned short* rp = R + (size_t)(m0 + row) * 256 + n0 + l16;
        rp[0]  = f2bf(__expf(-0.5f * (acc0[r] + p0)));
        rp[16] = f2bf(__expf(-0.5f * (acc1[r] + p1)));
    }
}

// ---------------- GEMM2: h = R @ WspT^T ; out = 1/(h+eps) ----
// Wave tile 16x32, block 64x32, grid = (2048/64, 512/32) = (32, 16) = 512 blocks.
__global__ __launch_bounds__(256) void gemm2_kernel(const unsigned char* __restrict__ ws,
                                                    float* __restrict__ out)
{
    const unsigned short* R    = (const unsigned short*)(ws + R_OFF);
    const unsigned short* WspT = (const unsigned short*)(ws + WSPT_OFF);

    const int lane = threadIdx.x & 63;
    const int w    = threadIdx.x >> 6;
    const int l16  = lane & 15;
    const int quad = lane >> 4;
    const int m0 = blockIdx.x * 64 + w * 16;
    const int n0 = blockIdx.y * 32;

    const unsigned short* aptr  = R    + (size_t)(m0 + l16) * 256 + quad * 8;
    const unsigned short* bptr0 = WspT + (size_t)(n0 + l16) * 256 + quad * 8;
    const unsigned short* bptr1 = bptr0 + 16 * 256;

    f32x4 acc0 = {0.f, 0.f, 0.f, 0.f}, acc1 = {0.f, 0.f, 0.f, 0.f};
    #pragma unroll
    for (int ks = 0; ks < 256; ks += 32) {
        bf16x8 af  = *(const bf16x8*)(aptr + ks);
        bf16x8 bf0 = *(const bf16x8*)(bptr0 + ks);
        bf16x8 bf1 = *(const bf16x8*)(bptr1 + ks);
        acc0 = __builtin_amdgcn_mfma_f32_16x16x32_bf16(af, bf0, acc0, 0, 0, 0);
        acc1 = __builtin_amdgcn_mfma_f32_16x16x32_bf16(af, bf1, acc1, 0, 0, 0);
    }

    #pragma unroll
    for (int r = 0; r < 4; ++r) {
        int row = quad * 4 + r;
        float* op = out + (size_t)(m0 + row) * 512 + n0 + l16;
        op[0]  = 1.f / (acc0[r] + EPS);
        op[16] = 1.f / (acc1[r] + EPS);
    }
}

// ================= Fallback (round-2 fp32 path, used if ws too small) =======
__global__ __launch_bounds__(256) void softplus_kernel(const float* __restrict__ raw,
                                                       float* __restrict__ wsp) {
    int i = blockIdx.x * 256 + threadIdx.x;
    if (i < K_SZ * D_SZ) wsp[i] = softplus_f(raw[i]);
}

__global__ __launch_bounds__(1024, 4) void fused_kernel(
    const float* __restrict__ x, const float* __restrict__ centers,
    const float* __restrict__ bandwidths, const float* __restrict__ raw_w,
    const float* __restrict__ wsp, float* __restrict__ out, int pre)
{
    __shared__ float xs[8][D_SZ + 4];
    __shared__ float rbfT[K_SZ][8];
    const int t  = threadIdx.x;
    const int b0 = blockIdx.x * 8;
    {
        const float4* xg = (const float4*)(x + (size_t)b0 * D_SZ);
        int row = t >> 7, col4 = t & 127;
        float4 v = xg[t];
        *(float4*)&xs[row][col4 << 2] = v;
    }
    __syncthreads();
    {
        const int r = t & 7, kslot = t >> 3;
        #pragma unroll
        for (int kc = 0; kc < 2; ++kc) {
            int k = kc * 128 + kslot;
            const float4* cg = (const float4*)(centers + (size_t)k * D_SZ);
            const float4* bg = (const float4*)(bandwidths + (size_t)k * D_SZ);
            float a0 = 0.f, a1 = 0.f, a2 = 0.f, a3 = 0.f;
            #pragma unroll 8
            for (int j = 0; j < 128; ++j) {
                float4 c = cg[j], w = bg[j];
                float4 xv = *(const float4*)&xs[r][j << 2];
                float d0 = xv.x - c.x, d1 = xv.y - c.y;
                float d2 = xv.z - c.z, d3 = xv.w - c.w;
                a0 = fmaf(d0 * d0, w.x, a0); a1 = fmaf(d1 * d1, w.y, a1);
                a2 = fmaf(d2 * d2, w.z, a2); a3 = fmaf(d3 * d3, w.w, a3);
            }
            rbfT[k][r] = __expf(-0.5f * ((a0 + a1) + (a2 + a3)));
        }
    }
    __syncthreads();
    {
        const int d = t & 511, half = t >> 9;
        float acc0 = 0.f, acc1 = 0.f, acc2 = 0.f, acc3 = 0.f;
        for (int k = 0; k < K_SZ; ++k) {
            float wv;
            if (pre) wv = wsp[(size_t)k * D_SZ + d];
            else     wv = softplus_f(raw_w[(size_t)k * D_SZ + d]);
            float4 rv = *(const float4*)&rbfT[k][half << 2];
            acc0 = fmaf(rv.x, wv, acc0); acc1 = fmaf(rv.y, wv, acc1);
            acc2 = fmaf(rv.z, wv, acc2); acc3 = fmaf(rv.w, wv, acc3);
        }
        const int rbase = b0 + (half << 2);
        out[(size_t)(rbase + 0) * D_SZ + d] = 1.f / (acc0 + EPS);
        out[(size_t)(rbase + 1) * D_SZ + d] = 1.f / (acc1 + EPS);
        out[(size_t)(rbase + 2) * D_SZ + d] = 1.f / (acc2 + EPS);
        out[(size_t)(rbase + 3) * D_SZ + d] = 1.f / (acc3 + EPS);
    }
}

extern "C" void kernel_launch(void* const* d_in, const int* in_sizes, int n_in,
                              void* d_out, int out_size, void* d_ws, size_t ws_size,
                              hipStream_t stream) {
    const float* x          = (const float*)d_in[0];
    const float* centers    = (const float*)d_in[1];
    const float* bandwidths = (const float*)d_in[2];
    const float* raw_w      = (const float*)d_in[3];
    float* out = (float*)d_out;

    if (ws_size >= WS_TOTAL) {
        unsigned char* ws = (unsigned char*)d_ws;
        prep_kernel<<<1344, 256, 0, stream>>>(x, centers, bandwidths, raw_w, ws);
        gemm1_kernel<<<dim3(32, 8), 256, 0, stream>>>(ws, ws);
        gemm2_kernel<<<dim3(32, 16), 256, 0, stream>>>(ws, out);
    } else {
        float* wsp = (float*)d_ws;
        const int pre = (ws_size >= (size_t)K_SZ * D_SZ * sizeof(float)) ? 1 : 0;
        if (pre) softplus_kernel<<<(K_SZ * D_SZ + 255) / 256, 256, 0, stream>>>(raw_w, wsp);
        fused_kernel<<<B_SZ / 8, 1024, 0, stream>>>(x, centers, bandwidths, raw_w, wsp, out, pre);
    }
}